// Round 1
// 185.568 us; speedup vs baseline: 1.0198x; 1.0198x over previous
//
#include <hip/hip_runtime.h>

typedef __attribute__((ext_vector_type(8))) short bf16x8;
typedef __attribute__((ext_vector_type(4))) float f32x4;
typedef __attribute__((ext_vector_type(4))) float f32x4v;   // native vector for nt ld/st

#define LDW 776   // 768 + 8 bf16 pad

static __device__ __forceinline__ unsigned short f2bf(float f) {
    unsigned u = __builtin_bit_cast(unsigned, f);
    u += 0x7fffu + ((u >> 16) & 1u);          // round-to-nearest-even
    return (unsigned short)(u >> 16);
}

#if __has_builtin(__builtin_amdgcn_cvt_pk_bf16_f32)
typedef __attribute__((ext_vector_type(2))) __bf16 bf16x2_t;
static __device__ __forceinline__ unsigned pack2(float a, float b) {
    bf16x2_t r = __builtin_amdgcn_cvt_pk_bf16_f32(a, b);   // lo=a, hi=b, RNE
    return __builtin_bit_cast(unsigned, r);
}
#else
static __device__ __forceinline__ unsigned pack2(float a, float b) {
    return ((unsigned)f2bf(b) << 16) | (unsigned)f2bf(a);
}
#endif

#define PF 6   // prefetch depth: 12 loads in flight per wave

// GEMM view: M=16 out-ch, K=768, N=32768 patches. Split-K x2, 16 waves/CU,
// explicit depth-6 software pipeline for memory-level parallelism.
// This revision: non-temporal input loads + output stores (pure streaming,
// zero reuse) so the 134 MB stream does not allocate in L2/L3.
__global__ __launch_bounds__(256, 4)
void cnn16_mfma(const float* __restrict__ in,
                const float* __restrict__ w1, const float* __restrict__ b1,
                const float* __restrict__ g1, const float* __restrict__ bt1,
                const float* __restrict__ m1, const float* __restrict__ v1,
                const float* __restrict__ w2, const float* __restrict__ b2,
                const float* __restrict__ g2, const float* __restrict__ bt2,
                const float* __restrict__ m2, const float* __restrict__ v2,
                const float* __restrict__ w3, const float* __restrict__ b3,
                float* __restrict__ out)
{
    __shared__ unsigned short wA[16 * LDW];                 // 24.8 KB bf16 weights
    __shared__ float part[16][64];                          // split-K combine
    __shared__ float cInv1[16], cBb1[16], cW2[64], cA2[4], cB2[4], cW3[4], cB3[1];

    const int tid = threadIdx.x;

    // ---- one-time staging: w1 -> bf16 LDS (float4 loads), folded BN consts ----
    // (w1 is reused by all 1024 blocks -> keep these loads CACHED, not nt)
#pragma unroll
    for (int j = 0; j < 12; ++j) {
        const int e = (tid + (j << 8)) << 2;                // float4-aligned elem idx
        const int m = e / 768;
        const int k = e - m * 768;
        const float4 w4 = *reinterpret_cast<const float4*>(w1 + e);
        uint2 pk; pk.x = pack2(w4.x, w4.y); pk.y = pack2(w4.z, w4.w);
        *reinterpret_cast<uint2*>(&wA[m * LDW + k]) = pk;
    }
    if (tid < 16) {
        const float iv = g1[tid] * rsqrtf(v1[tid] + 1e-5f);
        cInv1[tid] = iv;
        cBb1[tid]  = (b1[tid] - m1[tid]) * iv + bt1[tid];   // folds conv bias + BN1
    }
    if (tid < 64) cW2[tid] = w2[tid];
    if (tid < 4) {
        const float iv = g2[tid] * rsqrtf(v2[tid] + 1e-5f);
        cA2[tid] = iv;
        cB2[tid] = (b2[tid] - m2[tid]) * iv + bt2[tid];
        cW3[tid] = w3[tid];
    }
    if (tid == 0) cB3[0] = b3[0];
    __syncthreads();

    // ---- wave -> (tile, K-half) ----
    const int lane = tid & 63;
    const int w    = tid >> 6;                 // wave in block 0..3
    const int h    = w & 1;                    // K half
    const int t    = (blockIdx.x << 1) + (w >> 1);   // tile 0..2047
    const int b    = t >> 6;
    const int ph   = (t >> 1) & 31;
    const int pw0  = (t & 1) << 4;

    const int p = lane & 15;                   // patch within tile (N col)
    const int q = lane >> 4;                   // quad

    const unsigned short* wArow = wA + p * LDW + (q << 3);   // A[m=lane&15][k=q*8+j]
    const float* inb = in + (size_t)b * 786432 + (size_t)(ph << 4) * 512
                          + (size_t)(pw0 + p) * 16;
    const int step0 = h * 12;

    // ---- prologue: issue PF load-pairs (96B/lane in flight), non-temporal ----
    f32x4v plo[PF], phi[PF];
#pragma unroll
    for (int s = 0; s < PF; ++s) {
        const int k0p = ((step0 + s) << 5) + (q << 3);
        const float* src = inb + (k0p >> 8) * 262144 + ((k0p & 255) >> 4) * 512 + (k0p & 15);
        plo[s] = __builtin_nontemporal_load(reinterpret_cast<const f32x4v*>(src));
        phi[s] = __builtin_nontemporal_load(reinterpret_cast<const f32x4v*>(src + 4));
    }

    f32x4 acc = {0.f, 0.f, 0.f, 0.f};

#pragma unroll
    for (int s = 0; s < 12; ++s) {
        const int slot = s % PF;               // static under full unroll

        union { bf16x8 v; unsigned u[4]; } bf;
        bf.u[0] = pack2(plo[slot][0], plo[slot][1]);
        bf.u[1] = pack2(plo[slot][2], plo[slot][3]);
        bf.u[2] = pack2(phi[slot][0], phi[slot][1]);
        bf.u[3] = pack2(phi[slot][2], phi[slot][3]);

        // refill the slot for step s+PF (keeps 2*PF loads outstanding)
        if (s + PF < 12) {
            const int k0p = ((step0 + s + PF) << 5) + (q << 3);
            const float* src = inb + (k0p >> 8) * 262144 + ((k0p & 255) >> 4) * 512 + (k0p & 15);
            plo[slot] = __builtin_nontemporal_load(reinterpret_cast<const f32x4v*>(src));
            phi[slot] = __builtin_nontemporal_load(reinterpret_cast<const f32x4v*>(src + 4));
        }

        const bf16x8 af = *reinterpret_cast<const bf16x8*>(wArow + ((step0 + s) << 5));
        acc = __builtin_amdgcn_mfma_f32_16x16x32_bf16(af, bf.v, acc, 0, 0, 0);
    }

    // ---- split-K combine through LDS ----
#pragma unroll
    for (int r = 0; r < 4; ++r) part[(w << 2) + r][lane] = acc[r];
    __syncthreads();
    float accf[4];
#pragma unroll
    for (int r = 0; r < 4; ++r) accf[r] = acc[r] + part[((w ^ 1) << 2) + r][lane];

    // ---- epilogue: D[row=ch=q*4+r][col=patch=p] ----
    float zp[4] = {0.f, 0.f, 0.f, 0.f};
#pragma unroll
    for (int r = 0; r < 4; ++r) {
        const int ch = (q << 2) + r;
        float y = fmaf(accf[r], cInv1[ch], cBb1[ch]);
        y = fmaxf(y, 0.f);                                   // BN1 + ReLU
#pragma unroll
        for (int o = 0; o < 4; ++o) zp[o] = fmaf(y, cW2[o * 16 + ch], zp[o]);
    }

    float s = cB3[0];
#pragma unroll
    for (int o = 0; o < 4; ++o) {
        float z = zp[o];
        z += __shfl_xor(z, 16, 64);                          // combine quads
        z += __shfl_xor(z, 32, 64);
        z = fmaf(z, cA2[o], cB2[o]);                         // BN2
        z = fmaxf(z, 0.f);                                   // ReLU
        s = fmaf(z, cW3[o], s);                              // 1x1 conv 4->1
    }

    // ---- 16x upsample store (non-temporal): quad q rows 4q..4q+3; wave h rows 2h,2h+1 ----
    const f32x4v v4 = {s, s, s, s};
    float* ob = out + (size_t)b * 262144
                    + (size_t)((ph << 4) + (q << 2) + (h << 1)) * 512
                    + (size_t)(pw0 + p) * 16;
#pragma unroll
    for (int rr = 0; rr < 2; ++rr)
#pragma unroll
        for (int c = 0; c < 4; ++c)
            __builtin_nontemporal_store(v4, reinterpret_cast<f32x4v*>(ob + rr * 512 + (c << 2)));
}

extern "C" void kernel_launch(void* const* d_in, const int* in_sizes, int n_in,
                              void* d_out, int out_size, void* d_ws, size_t ws_size,
                              hipStream_t stream) {
    const float* in  = (const float*)d_in[0];
    const float* w1  = (const float*)d_in[1];
    const float* b1  = (const float*)d_in[2];
    const float* g1  = (const float*)d_in[3];
    const float* bt1 = (const float*)d_in[4];
    const float* m1  = (const float*)d_in[5];
    const float* v1  = (const float*)d_in[6];
    const float* w2  = (const float*)d_in[7];
    const float* b2  = (const float*)d_in[8];
    const float* g2  = (const float*)d_in[9];
    const float* bt2 = (const float*)d_in[10];
    const float* m2  = (const float*)d_in[11];
    const float* v2  = (const float*)d_in[12];
    const float* w3  = (const float*)d_in[13];
    const float* b3  = (const float*)d_in[14];
    float* out = (float*)d_out;

    cnn16_mfma<<<dim3(1024), dim3(256), 0, stream>>>(
        in, w1, b1, g1, bt1, m1, v1, w2, b2, g2, bt2, m2, v2, w3, b3, out);
}